// Round 8
// baseline (53.929 us; speedup 1.0000x reference)
//
#include <hip/hip_runtime.h>
#include <hip/hip_bf16.h>

#define B_   256
#define T_   2048
#define D_   100
#define U_   50
#define S_   32
#define SEC_ 64

typedef __attribute__((ext_vector_type(8))) short short8;
typedef __attribute__((ext_vector_type(4))) float f32x4;

__device__ __forceinline__ float fast_tanh(float x) {
    // tanh(x) = 1 - 2/(1 + e^{2x}); safe at +-inf
    float e = __expf(2.0f * x);
    return 1.0f - 2.0f * __builtin_amdgcn_rcpf(1.0f + e);
}

__device__ __forceinline__ short f2bf(float f) {
    union { __hip_bfloat16 h; unsigned short u; } cv;
    cv.h = __float2bfloat16(f);  // RNE
    return (short)cv.u;
}

__device__ __forceinline__ short8 pack8(f32x4 a, f32x4 b) {
    short8 r;
    r[0] = f2bf(a[0]); r[1] = f2bf(a[1]); r[2] = f2bf(a[2]); r[3] = f2bf(a[3]);
    r[4] = f2bf(b[0]); r[5] = f2bf(b[1]); r[6] = f2bf(b[2]); r[7] = f2bf(b[3]);
    return r;
}

// wu_proj[b][u] = dot(user_vec[b], wu[u]) + bw[u]
__global__ __launch_bounds__(64) void wu_proj_kernel(
    const float* __restrict__ user_vec, const float* __restrict__ wu,
    const float* __restrict__ bw, float* __restrict__ wup) {
    int b = blockIdx.x;
    int u = threadIdx.x;
    if (u >= U_) return;
    const f32x4* uv4 = reinterpret_cast<const f32x4*>(user_vec + b * D_);
    const f32x4* wu4 = reinterpret_cast<const f32x4*>(wu + u * D_);
    float acc = 0.f;
#pragma unroll
    for (int c = 0; c < D_ / 4; ++c) {
        f32x4 a = uv4[c];
        f32x4 w = wu4[c];
        acc = __builtin_fmaf(a[0], w[0], acc);
        acc = __builtin_fmaf(a[1], w[1], acc);
        acc = __builtin_fmaf(a[2], w[2], acc);
        acc = __builtin_fmaf(a[3], w[3], acc);
    }
    wup[b * U_ + u] = acc + bw[u];
}

// Load one 16-word m-tile into X[7] (per-lane f32x4 chunks).
#define LOADX(X, base, mm) do {                                          \
    const float* row_ = (base) + (16 * (mm) + li) * D_;                  \
    X[0] = *reinterpret_cast<const f32x4*>(row_ + c0);                   \
    X[1] = *reinterpret_cast<const f32x4*>(row_ + c0 + 16);              \
    X[2] = *reinterpret_cast<const f32x4*>(row_ + c0 + 32);              \
    X[3] = *reinterpret_cast<const f32x4*>(row_ + c0 + 48);              \
    X[4] = *reinterpret_cast<const f32x4*>(row_ + c0 + 64);              \
    X[5] = *reinterpret_cast<const f32x4*>(row_ + c0 + 80);              \
    X[6] = *reinterpret_cast<const f32x4*>(row_ + 96) * mg;              \
} while (0)

// Per-m-tile compute: proj MFMA, e-scores, p=exp(e-Mb), pooling FMA.
#define COMPUTE_M(X) do {                                                \
    short8 af[4];                                                        \
    af[0] = pack8(X[0], X[1]);                                           \
    af[1] = pack8(X[2], X[3]);                                           \
    af[2] = pack8(X[4], X[5]);                                           \
    af[3] = pack8(X[6], zero4);                                          \
    f32x4 acc[4];                                                        \
    _Pragma("unroll")                                                    \
    for (int n = 0; n < 4; ++n) acc[n] = (f32x4){0.f, 0.f, 0.f, 0.f};    \
    _Pragma("unroll")                                                    \
    for (int ks = 0; ks < 4; ++ks) {                                     \
        _Pragma("unroll")                                                \
        for (int n = 0; n < 4; ++n) {                                    \
            acc[n] = __builtin_amdgcn_mfma_f32_16x16x32_bf16(            \
                af[ks], whb[n * 4 + ks][l], acc[n], 0, 0, 0);            \
        }                                                                \
    }                                                                    \
    float p[4];                                                          \
    _Pragma("unroll")                                                    \
    for (int r = 0; r < 4; ++r) {                                        \
        float t = 0.f;                                                   \
        _Pragma("unroll")                                                \
        for (int n = 0; n < 4; ++n)                                      \
            t = __builtin_fmaf(vwl[n], fast_tanh(acc[n][r] + gl[n]), t); \
        t += __shfl_xor(t, 1);                                           \
        t += __shfl_xor(t, 2);                                           \
        t += __shfl_xor(t, 4);                                           \
        t += __shfl_xor(t, 8);                                           \
        p[r] = __expf(t - Mb);                                           \
    }                                                                    \
    tsum += (p[0] + p[1]) + (p[2] + p[3]);                               \
    const int src = (li >> 2) << 4;                                      \
    const float w0 = __shfl(p[0], src);                                  \
    const float w1 = __shfl(p[1], src);                                  \
    const float w2 = __shfl(p[2], src);                                  \
    const float w3 = __shfl(p[3], src);                                  \
    const float wa = (li & 1) ? w1 : w0;                                 \
    const float wb = (li & 1) ? w3 : w2;                                 \
    const float wgt = (li & 2) ? wb : wa;                                \
    _Pragma("unroll")                                                    \
    for (int j = 0; j < 7; ++j)                                          \
        pool[j] = pool[j] + X[j] * wgt;                                  \
} while (0)

// Per-section epilogue: denom fold, pool butterfly, bounce, store, reset.
// Wave-private (no __syncthreads) — only lgkmcnt ordering on poolbuf[wid].
#define EPILOG(PO) do {                                                  \
    float ts = tsum;                                                     \
    ts += __shfl_xor(ts, 16);                                            \
    ts += __shfl_xor(ts, 32);                                            \
    _Pragma("unroll")                                                    \
    for (int j = 0; j < 7; ++j) {                                        \
        _Pragma("unroll")                                                \
        for (int c = 0; c < 4; ++c) {                                    \
            float v = pool[j][c];                                        \
            v += __shfl_xor(v, 1);                                       \
            v += __shfl_xor(v, 2);                                       \
            v += __shfl_xor(v, 4);                                       \
            v += __shfl_xor(v, 8);                                       \
            pool[j][c] = v;                                              \
        }                                                                \
    }                                                                    \
    const float inv_ = 1.0f / ts;                                        \
    if (li == 0) {                                                       \
        _Pragma("unroll")                                                \
        for (int j = 0; j < 6; ++j) {                                    \
            _Pragma("unroll")                                            \
            for (int c = 0; c < 4; ++c) {                                \
                const int k = 32 * (j >> 1) + 16 * (j & 1) + 4 * g + c;  \
                poolbuf[wid][k] = pool[j][c];                            \
            }                                                            \
        }                                                                \
        if (g == 0) {                                                    \
            _Pragma("unroll")                                            \
            for (int c = 0; c < 4; ++c) poolbuf[wid][96 + c] = pool[6][c]; \
        }                                                                \
    }                                                                    \
    asm volatile("s_waitcnt lgkmcnt(0)" ::: "memory");                   \
    {                                                                    \
        float* po_ = (PO);                                               \
        po_[l] = poolbuf[wid][l] * inv_;                                 \
        if (l < D_ - SEC_) po_[SEC_ + l] = poolbuf[wid][SEC_ + l] * inv_; \
    }                                                                    \
    _Pragma("unroll")                                                    \
    for (int j = 0; j < 7; ++j) pool[j] = zero4;                         \
    tsum = 0.f;                                                          \
} while (0)

// Streaming kernel: each wave owns 2 consecutive sections (same b),
// 8 m-tiles straight-line with 2-buffer ping-pong crossing the section
// boundary; section-0 epilogue overlaps section-1's in-flight loads.
// Single __syncthreads (whb staging); no barriers in steady state.
__global__ __launch_bounds__(256, 2) void attn_pool_v8(
    const float* __restrict__ sent,     // [B, T, D]
    const float* __restrict__ vw,       // [U]
    const float* __restrict__ wh,       // [U, D]
    const float* __restrict__ wup_all,  // [B, U]
    float* __restrict__ out) {          // [B, S, D]
    __shared__ short8 whb[16][64];      // bf16 B-fragments of wh = 16 KB
    __shared__ float  poolbuf[4][128];  // per-wave store bounce = 2 KB

    const int tid = threadIdx.x;
    const int wid = tid >> 6;
    const int l   = tid & 63;
    const int g   = l >> 4;
    const int li  = l & 15;

    const int W  = blockIdx.x * 4 + wid;  // global wave id, 0..4095
    const int b  = W >> 4;                // 16 waves per batch row
    const int sp = W & 15;                // section pair
    const float* sec0 = sent + ((size_t)b * T_ + (size_t)(2 * sp) * SEC_) * D_;
    const float* sec1 = sec0 + SEC_ * D_;
    const float* wup  = wup_all + b * U_;

    const float mg = (g == 0) ? 1.f : 0.f;  // ks=3 chunk valid only for g==0
    const int c0 = 4 * g;
    const f32x4 zero4 = (f32x4){0.f, 0.f, 0.f, 0.f};

    // ---- issue first section loads before the prologue ----
    f32x4 xA[7], xB[7];
    LOADX(xA, sec0, 0);
    LOADX(xB, sec0, 1);

    // ---- prologue: wh(f32) -> bf16 B-fragments in LDS (once per block) ----
#pragma unroll
    for (int j = 0; j < 4; ++j) {
        const int idx = tid + 256 * j;
        const int pli = idx & 15;
        const int pg  = (idx >> 4) & 3;
        const int pks = (idx >> 6) & 3;
        const int pn  = idx >> 8;
        const int u   = 16 * pn + pli;
        const bool uv = (u < U_);
        const int k0  = 32 * pks + 4 * pg;
        const bool v1 = uv && (k0 <= D_ - 4);
        const bool v2 = uv && (k0 + 16 <= D_ - 4);
        const float* rowp = wh + (uv ? u : 0) * D_;
        f32x4 a  = *reinterpret_cast<const f32x4*>(rowp + (v1 ? k0 : 0));
        f32x4 bb = *reinterpret_cast<const f32x4*>(rowp + (v2 ? k0 + 16 : 0));
        a  *= (v1 ? 1.f : 0.f);
        bb *= (v2 ? 1.f : 0.f);
        whb[idx >> 6][idx & 63] = pack8(a, bb);
    }

    // per-lane vw / wu_proj slices (unit u = 16n + li)
    float vwl[4], gl[4];
#pragma unroll
    for (int n = 0; n < 4; ++n) {
        const int uu = 16 * n + li;
        const bool uv = (uu < U_);
        const int uc = uv ? uu : 0;
        const float rv = uv ? 1.f : 0.f;
        vwl[n] = vw[uc] * rv;
        gl[n]  = wup[uc] * rv;
    }
    // Mb = sum_u |vw[u]|  (>= max |e|), replicated across lanes
    float Mb = fabsf(vwl[0]) + fabsf(vwl[1]) + fabsf(vwl[2]) + fabsf(vwl[3]);
    Mb += __shfl_xor(Mb, 1);
    Mb += __shfl_xor(Mb, 2);
    Mb += __shfl_xor(Mb, 4);
    Mb += __shfl_xor(Mb, 8);
    __syncthreads();

    // ---- steady state: 8 m-tiles, barrier-free, cross-section pipeline ----
    f32x4 pool[7];
#pragma unroll
    for (int j = 0; j < 7; ++j) pool[j] = zero4;
    float tsum = 0.f;

    float* po0 = out + ((size_t)b * S_ + 2 * sp) * D_;
    float* po1 = po0 + D_;

    COMPUTE_M(xA); LOADX(xA, sec0, 2);
    COMPUTE_M(xB); LOADX(xB, sec0, 3);
    COMPUTE_M(xA); LOADX(xA, sec1, 0);
    COMPUTE_M(xB); LOADX(xB, sec1, 1);
    EPILOG(po0);                         // overlaps sec1 m0/m1 HBM flight
    COMPUTE_M(xA); LOADX(xA, sec1, 2);
    COMPUTE_M(xB); LOADX(xB, sec1, 3);
    COMPUTE_M(xA);
    COMPUTE_M(xB);
    EPILOG(po1);
}

extern "C" void kernel_launch(void* const* d_in, const int* in_sizes, int n_in,
                              void* d_out, int out_size, void* d_ws, size_t ws_size,
                              hipStream_t stream) {
    const float* sent = (const float*)d_in[0];
    const float* uvec = (const float*)d_in[1];
    const float* vw   = (const float*)d_in[2];
    const float* wh   = (const float*)d_in[3];
    const float* wu   = (const float*)d_in[4];
    const float* bw   = (const float*)d_in[5];
    float* out = (float*)d_out;
    float* wup = (float*)d_ws;  // B_*U_ floats

    wu_proj_kernel<<<dim3(B_), dim3(64), 0, stream>>>(uvec, wu, bw, wup);
    attn_pool_v8<<<dim3(B_ * S_ / 8), dim3(256), 0, stream>>>(sent, vw, wh, wup, out);
}

// Round 9
// 53.322 us; speedup vs baseline: 1.0114x; 1.0114x over previous
//
#include <hip/hip_runtime.h>
#include <hip/hip_bf16.h>

#define B_   256
#define T_   2048
#define D_   100
#define U_   50
#define S_   32
#define SEC_ 64

typedef __attribute__((ext_vector_type(8))) short short8;
typedef __attribute__((ext_vector_type(4))) float f32x4;

__device__ __forceinline__ float fast_tanh(float x) {
    // tanh(x) = 1 - 2/(1 + e^{2x}); safe at +-inf
    float e = __expf(2.0f * x);
    return 1.0f - 2.0f * __builtin_amdgcn_rcpf(1.0f + e);
}

__device__ __forceinline__ short f2bf(float f) {
    union { __hip_bfloat16 h; unsigned short u; } cv;
    cv.h = __float2bfloat16(f);  // RNE
    return (short)cv.u;
}

__device__ __forceinline__ short8 pack8(f32x4 a, f32x4 b) {
    short8 r;
    r[0] = f2bf(a[0]); r[1] = f2bf(a[1]); r[2] = f2bf(a[2]); r[3] = f2bf(a[3]);
    r[4] = f2bf(b[0]); r[5] = f2bf(b[1]); r[6] = f2bf(b[2]); r[7] = f2bf(b[3]);
    return r;
}

// VALU lane-reduction over the 16 lanes of a DPP row (li direction):
// v += row_ror:8/4/2/1 — all 16 lanes end with the full row sum.
template<int CTRL>
__device__ __forceinline__ float ror_add(float v) {
    union { float f; int i; } in, out;
    in.f = v;
    out.i = __builtin_amdgcn_update_dpp(0, in.i, CTRL, 0xF, 0xF, true);
    return v + out.f;
}
__device__ __forceinline__ float fold16(float v) {
    v = ror_add<0x128>(v);  // row_ror:8
    v = ror_add<0x124>(v);  // row_ror:4
    v = ror_add<0x122>(v);  // row_ror:2
    v = ror_add<0x121>(v);  // row_ror:1
    return v;
}

// wu_proj[b][u] = dot(user_vec[b], wu[u]) + bw[u]
__global__ __launch_bounds__(64) void wu_proj_kernel(
    const float* __restrict__ user_vec, const float* __restrict__ wu,
    const float* __restrict__ bw, float* __restrict__ wup) {
    int b = blockIdx.x;
    int u = threadIdx.x;
    if (u >= U_) return;
    const f32x4* uv4 = reinterpret_cast<const f32x4*>(user_vec + b * D_);
    const f32x4* wu4 = reinterpret_cast<const f32x4*>(wu + u * D_);
    float acc = 0.f;
#pragma unroll
    for (int c = 0; c < D_ / 4; ++c) {
        f32x4 a = uv4[c];
        f32x4 w = wu4[c];
        acc = __builtin_fmaf(a[0], w[0], acc);
        acc = __builtin_fmaf(a[1], w[1], acc);
        acc = __builtin_fmaf(a[2], w[2], acc);
        acc = __builtin_fmaf(a[3], w[3], acc);
    }
    wup[b * U_ + u] = acc + bw[u];
}

// Load one 16-word m-tile into X[7] (per-lane f32x4 chunks, row = word = li).
#define LOADX(X, mm) do {                                                \
    const float* row_ = secbase + (16 * (mm) + li) * D_;                 \
    X[0] = *reinterpret_cast<const f32x4*>(row_ + c0);                   \
    X[1] = *reinterpret_cast<const f32x4*>(row_ + c0 + 16);              \
    X[2] = *reinterpret_cast<const f32x4*>(row_ + c0 + 32);              \
    X[3] = *reinterpret_cast<const f32x4*>(row_ + c0 + 48);              \
    X[4] = *reinterpret_cast<const f32x4*>(row_ + c0 + 64);              \
    X[5] = *reinterpret_cast<const f32x4*>(row_ + c0 + 80);              \
    X[6] = *reinterpret_cast<const f32x4*>(row_ + 96) * mg;              \
} while (0)

// Per-m-tile compute, shfl-free:
//   MFMA#1 (swapped): acc[n] = Wh · X^T -> lane holds units 16n+4g+r of
//   word=li. t = vw*tanh(acc+gl). MFMA#2 (A=ones): e[word=li] replicated
//   in-lane. p = exp(e-Mb) is already in the pooling lane -> pure FMAs.
#define COMPUTE_M(X) do {                                                \
    short8 af[4];                                                        \
    af[0] = pack8(X[0], X[1]);                                           \
    af[1] = pack8(X[2], X[3]);                                           \
    af[2] = pack8(X[4], X[5]);                                           \
    af[3] = pack8(X[6], zero4);                                          \
    f32x4 acc[4];                                                        \
    _Pragma("unroll")                                                    \
    for (int n = 0; n < 4; ++n) acc[n] = (f32x4){0.f, 0.f, 0.f, 0.f};    \
    _Pragma("unroll")                                                    \
    for (int ks = 0; ks < 4; ++ks) {                                     \
        _Pragma("unroll")                                                \
        for (int n = 0; n < 4; ++n) {                                    \
            acc[n] = __builtin_amdgcn_mfma_f32_16x16x32_bf16(            \
                whb[n * 4 + ks][l], af[ks], acc[n], 0, 0, 0);            \
        }                                                                \
    }                                                                    \
    f32x4 t[4];                                                          \
    _Pragma("unroll")                                                    \
    for (int n = 0; n < 4; ++n) {                                        \
        _Pragma("unroll")                                                \
        for (int r = 0; r < 4; ++r)                                      \
            t[n][r] = vwl2[n][r] * fast_tanh(acc[n][r] + gl2[n][r]);     \
    }                                                                    \
    f32x4 e4 = (f32x4){0.f, 0.f, 0.f, 0.f};                              \
    e4 = __builtin_amdgcn_mfma_f32_16x16x32_bf16(                        \
        a2ones, pack8(t[0], t[1]), e4, 0, 0, 0);                         \
    e4 = __builtin_amdgcn_mfma_f32_16x16x32_bf16(                        \
        a2ones, pack8(t[2], t[3]), e4, 0, 0, 0);                         \
    const float p = __expf(e4[0] - Mb);                                  \
    tsum += p;                                                           \
    _Pragma("unroll")                                                    \
    for (int j = 0; j < 7; ++j)                                          \
        pool[j] = pool[j] + X[j] * p;                                    \
} while (0)

// Block = 4 waves = 4 sections; wave-private epilogue (no steady barriers).
__global__ __launch_bounds__(256, 2) void attn_pool_v9(
    const float* __restrict__ sent,     // [B, T, D]
    const float* __restrict__ vw,       // [U]
    const float* __restrict__ wh,       // [U, D]
    const float* __restrict__ wup_all,  // [B, U]
    float* __restrict__ out) {          // [B, S, D]
    __shared__ short8 whb[16][64];      // bf16 Wh fragments = 16 KB
    __shared__ float  poolbuf[4][128];  // per-wave store bounce = 2 KB

    const int tid = threadIdx.x;
    const int wid = tid >> 6;
    const int l   = tid & 63;
    const int g   = l >> 4;
    const int li  = l & 15;

    const int b = blockIdx.x >> 3;
    const int s = (blockIdx.x & 7) * 4 + wid;
    const float* secbase = sent + ((size_t)b * T_ + (size_t)s * SEC_) * D_;
    const float* wup = wup_all + b * U_;

    const float mg = (g == 0) ? 1.f : 0.f;  // ks=3 chunk valid only for g==0
    const int c0 = 4 * g;
    const f32x4 zero4 = (f32x4){0.f, 0.f, 0.f, 0.f};

    // ---- issue first section loads before the prologue ----
    f32x4 xA[7], xB[7];
    LOADX(xA, 0);
    LOADX(xB, 1);

    // ---- prologue: wh(f32) -> bf16 fragments in LDS (once per block) ----
#pragma unroll
    for (int j = 0; j < 4; ++j) {
        const int idx = tid + 256 * j;
        const int pli = idx & 15;
        const int pg  = (idx >> 4) & 3;
        const int pks = (idx >> 6) & 3;
        const int pn  = idx >> 8;
        const int u   = 16 * pn + pli;
        const bool uv = (u < U_);
        const int k0  = 32 * pks + 4 * pg;
        const bool v1 = uv && (k0 <= D_ - 4);
        const bool v2 = uv && (k0 + 16 <= D_ - 4);
        const float* rowp = wh + (uv ? u : 0) * D_;
        f32x4 a  = *reinterpret_cast<const f32x4*>(rowp + (v1 ? k0 : 0));
        f32x4 bb = *reinterpret_cast<const f32x4*>(rowp + (v2 ? k0 + 16 : 0));
        a  *= (v1 ? 1.f : 0.f);
        bb *= (v2 ? 1.f : 0.f);
        whb[idx >> 6][idx & 63] = pack8(a, bb);
    }

    // ---- per-lane vw / wu_proj for units u = 16n + 4g + r ----
    f32x4 vwl2[4], gl2[4];
#pragma unroll
    for (int n = 0; n < 4; ++n) {
#pragma unroll
        for (int r = 0; r < 4; ++r) {
            const int uu = 16 * n + 4 * g + r;
            const bool uv = (uu < U_);
            const int uc = uv ? uu : 0;
            const float rv = uv ? 1.f : 0.f;
            vwl2[n][r] = vw[uc] * rv;
            gl2[n][r]  = wup[uc] * rv;
        }
    }
    // Mb = sum_u |vw[u]| (>= max|e|): per-lane partial covers g's quarter;
    // fold over g with 2 shfls (once per wave).
    float Mb = 0.f;
#pragma unroll
    for (int n = 0; n < 4; ++n)
#pragma unroll
        for (int r = 0; r < 4; ++r) Mb += fabsf(vwl2[n][r]);
    Mb += __shfl_xor(Mb, 16);
    Mb += __shfl_xor(Mb, 32);

    // all-ones bf16 A-fragment for the reduction MFMA
    short8 a2ones;
#pragma unroll
    for (int i = 0; i < 8; ++i) a2ones[i] = (short)0x3F80;

    __syncthreads();

    // ---- 4 m-tiles, ping-pong loads, zero cross-lane in steady state ----
    f32x4 pool[7];
#pragma unroll
    for (int j = 0; j < 7; ++j) pool[j] = zero4;
    float tsum = 0.f;

    COMPUTE_M(xA); LOADX(xA, 2);
    COMPUTE_M(xB); LOADX(xB, 3);
    COMPUTE_M(xA);
    COMPUTE_M(xB);

    // ---- epilogue: li-direction reductions via DPP (VALU, no DS) ----
    const float inv = 1.0f / fold16(tsum);
#pragma unroll
    for (int j = 0; j < 7; ++j) {
#pragma unroll
        for (int c = 0; c < 4; ++c) pool[j][c] = fold16(pool[j][c]);
    }

    // ---- store via tiny per-wave LDS bounce (coalesced global store) ----
    if (li == 0) {
#pragma unroll
        for (int j = 0; j < 6; ++j) {
#pragma unroll
            for (int c = 0; c < 4; ++c) {
                const int k = 32 * (j >> 1) + 16 * (j & 1) + 4 * g + c;
                poolbuf[wid][k] = pool[j][c];
            }
        }
        if (g == 0) {
#pragma unroll
            for (int c = 0; c < 4; ++c) poolbuf[wid][96 + c] = pool[6][c];
        }
    }
    asm volatile("s_waitcnt lgkmcnt(0)" ::: "memory");

    float* po = out + ((size_t)b * S_ + s) * D_;
    po[l] = poolbuf[wid][l] * inv;
    if (l < D_ - SEC_) po[SEC_ + l] = poolbuf[wid][SEC_ + l] * inv;
}

extern "C" void kernel_launch(void* const* d_in, const int* in_sizes, int n_in,
                              void* d_out, int out_size, void* d_ws, size_t ws_size,
                              hipStream_t stream) {
    const float* sent = (const float*)d_in[0];
    const float* uvec = (const float*)d_in[1];
    const float* vw   = (const float*)d_in[2];
    const float* wh   = (const float*)d_in[3];
    const float* wu   = (const float*)d_in[4];
    const float* bw   = (const float*)d_in[5];
    float* out = (float*)d_out;
    float* wup = (float*)d_ws;  // B_*U_ floats

    wu_proj_kernel<<<dim3(B_), dim3(64), 0, stream>>>(uvec, wu, bw, wup);
    attn_pool_v9<<<dim3(B_ * S_ / 4), dim3(256), 0, stream>>>(sent, vw, wh, wup, out);
}

// Round 10
// 42.696 us; speedup vs baseline: 1.2631x; 1.2489x over previous
//
#include <hip/hip_runtime.h>
#include <hip/hip_bf16.h>

#define B_   256
#define T_   2048
#define D_   100
#define U_   50
#define S_   32
#define SEC_ 64

typedef __attribute__((ext_vector_type(8))) short short8;
typedef __attribute__((ext_vector_type(4))) float f32x4;

__device__ __forceinline__ float fast_tanh(float x) {
    // tanh(x) = 1 - 2/(1 + e^{2x}); safe at +-inf
    float e = __expf(2.0f * x);
    return 1.0f - 2.0f * __builtin_amdgcn_rcpf(1.0f + e);
}

__device__ __forceinline__ short f2bf(float f) {
    union { __hip_bfloat16 h; unsigned short u; } cv;
    cv.h = __float2bfloat16(f);  // RNE
    return (short)cv.u;
}

__device__ __forceinline__ short8 pack8(f32x4 a, f32x4 b) {
    short8 r;
    r[0] = f2bf(a[0]); r[1] = f2bf(a[1]); r[2] = f2bf(a[2]); r[3] = f2bf(a[3]);
    r[4] = f2bf(b[0]); r[5] = f2bf(b[1]); r[6] = f2bf(b[2]); r[7] = f2bf(b[3]);
    return r;
}

// VALU lane-reduction over the 16 lanes of a DPP row (li direction).
template<int CTRL>
__device__ __forceinline__ float ror_add(float v) {
    union { float f; int i; } in, out;
    in.f = v;
    out.i = __builtin_amdgcn_update_dpp(0, in.i, CTRL, 0xF, 0xF, true);
    return v + out.f;
}
__device__ __forceinline__ float fold16(float v) {
    v = ror_add<0x128>(v);  // row_ror:8
    v = ror_add<0x124>(v);  // row_ror:4
    v = ror_add<0x122>(v);  // row_ror:2
    v = ror_add<0x121>(v);  // row_ror:1
    return v;
}

// Wave-LINEAR global load of one 16x100 m-tile (1600 floats):
// 6 x f32x4 (1024 B contiguous each) + 1 x f32 (256 B contiguous).
#define LOADY(Y, Y6, mm) do {                                            \
    const float* p_ = secm + 1600 * (mm);                                \
    Y[0] = *reinterpret_cast<const f32x4*>(p_ + 4 * l);                  \
    Y[1] = *reinterpret_cast<const f32x4*>(p_ + 256 + 4 * l);            \
    Y[2] = *reinterpret_cast<const f32x4*>(p_ + 512 + 4 * l);            \
    Y[3] = *reinterpret_cast<const f32x4*>(p_ + 768 + 4 * l);            \
    Y[4] = *reinterpret_cast<const f32x4*>(p_ + 1024 + 4 * l);           \
    Y[5] = *reinterpret_cast<const f32x4*>(p_ + 1280 + 4 * l);           \
    Y6   = p_[1536 + l];                                                 \
} while (0)

// Bounce linear regs through wave-private LDS; read back fragment layout
// X[j] = row li, cols 4g+16j (stride-100 rows: uniform banks, no excess
// conflict; writes fully contiguous).
#define STAGE_READ(Y, Y6, X) do {                                        \
    _Pragma("unroll")                                                    \
    for (int j = 0; j < 6; ++j)                                          \
        *reinterpret_cast<f32x4*>(sb + 256 * j + 4 * l) = Y[j];          \
    sb[1536 + l] = Y6;                                                   \
    asm volatile("s_waitcnt lgkmcnt(0)" ::: "memory");                   \
    _Pragma("unroll")                                                    \
    for (int j = 0; j < 6; ++j)                                          \
        X[j] = *reinterpret_cast<const f32x4*>(sb + li * 100 + 4 * g + 16 * j); \
    X[6] = *reinterpret_cast<const f32x4*>(sb + li * 100 + 96) * mg;     \
} while (0)

// Per-m-tile compute, shfl-free (v9): swapped MFMA puts units on rows,
// word=li on cols; ones-MFMA reduces units; p lands in the pooling lane.
#define COMPUTE_M(X) do {                                                \
    short8 af[4];                                                        \
    af[0] = pack8(X[0], X[1]);                                           \
    af[1] = pack8(X[2], X[3]);                                           \
    af[2] = pack8(X[4], X[5]);                                           \
    af[3] = pack8(X[6], zero4);                                          \
    f32x4 acc[4];                                                        \
    _Pragma("unroll")                                                    \
    for (int n = 0; n < 4; ++n) acc[n] = (f32x4){0.f, 0.f, 0.f, 0.f};    \
    _Pragma("unroll")                                                    \
    for (int ks = 0; ks < 4; ++ks) {                                     \
        _Pragma("unroll")                                                \
        for (int n = 0; n < 4; ++n) {                                    \
            acc[n] = __builtin_amdgcn_mfma_f32_16x16x32_bf16(            \
                whb[n * 4 + ks][l], af[ks], acc[n], 0, 0, 0);            \
        }                                                                \
    }                                                                    \
    f32x4 t[4];                                                          \
    _Pragma("unroll")                                                    \
    for (int n = 0; n < 4; ++n) {                                        \
        _Pragma("unroll")                                                \
        for (int r = 0; r < 4; ++r)                                      \
            t[n][r] = vwl2[n][r] * fast_tanh(acc[n][r] + gl2[n][r]);     \
    }                                                                    \
    f32x4 e4 = (f32x4){0.f, 0.f, 0.f, 0.f};                              \
    e4 = __builtin_amdgcn_mfma_f32_16x16x32_bf16(                        \
        a2ones, pack8(t[0], t[1]), e4, 0, 0, 0);                         \
    e4 = __builtin_amdgcn_mfma_f32_16x16x32_bf16(                        \
        a2ones, pack8(t[2], t[3]), e4, 0, 0, 0);                         \
    const float p = __expf(e4[0] - Mb);                                  \
    tsum += p;                                                           \
    _Pragma("unroll")                                                    \
    for (int j = 0; j < 7; ++j)                                          \
        pool[j] = pool[j] + X[j] * p;                                    \
} while (0)

// Single fused kernel. Block = 4 waves = 4 sections of one batch row.
// wu_proj computed in-prologue (wave 0) -> LDS. Global reads wave-linear.
__global__ __launch_bounds__(256, 2) void attn_pool_v10(
    const float* __restrict__ sent,     // [B, T, D]
    const float* __restrict__ user_vec, // [B, USER_DIM]
    const float* __restrict__ vw,       // [U]
    const float* __restrict__ wh,       // [U, D]
    const float* __restrict__ wu,       // [U, USER_DIM]
    const float* __restrict__ bw,       // [U]
    float* __restrict__ out) {          // [B, S, D]
    __shared__ short8 whb[16][64];                    // 16 KB
    __shared__ __align__(16) float xstage[4][1600];   // 25.6 KB (wave-private)
    __shared__ float wup_s[64];
    __shared__ float poolbuf[4][128];                 // 2 KB

    const int tid = threadIdx.x;
    const int wid = tid >> 6;
    const int l   = tid & 63;
    const int g   = l >> 4;
    const int li  = l & 15;

    const int b = blockIdx.x >> 3;
    const int s = (blockIdx.x & 7) * 4 + wid;
    const float* secm = sent + ((size_t)b * T_ + (size_t)s * SEC_) * D_;
    float* sb = &xstage[wid][0];

    const float mg = (g == 0) ? 1.f : 0.f;
    const f32x4 zero4 = (f32x4){0.f, 0.f, 0.f, 0.f};

    // ---- issue first two m-tile loads (wave-linear, 14 instrs) ----
    f32x4 yA[6], yB[6];
    float y6A, y6B;
    LOADY(yA, y6A, 0);
    LOADY(yB, y6B, 1);

    // ---- prologue A: wh(f32) -> bf16 fragments in LDS ----
#pragma unroll
    for (int j = 0; j < 4; ++j) {
        const int idx = tid + 256 * j;
        const int pli = idx & 15;
        const int pg  = (idx >> 4) & 3;
        const int pks = (idx >> 6) & 3;
        const int pn  = idx >> 8;
        const int u   = 16 * pn + pli;
        const bool uv = (u < U_);
        const int k0  = 32 * pks + 4 * pg;
        const bool v1 = uv && (k0 <= D_ - 4);
        const bool v2 = uv && (k0 + 16 <= D_ - 4);
        const float* rowp = wh + (uv ? u : 0) * D_;
        f32x4 a  = *reinterpret_cast<const f32x4*>(rowp + (v1 ? k0 : 0));
        f32x4 bb = *reinterpret_cast<const f32x4*>(rowp + (v2 ? k0 + 16 : 0));
        a  *= (v1 ? 1.f : 0.f);
        bb *= (v2 ? 1.f : 0.f);
        whb[idx >> 6][idx & 63] = pack8(a, bb);
    }

    // ---- prologue B: fused wu_proj (wave 0, one unit per lane) ----
    if (tid < U_) {
        const f32x4* uv4 = reinterpret_cast<const f32x4*>(user_vec + b * D_);
        const f32x4* wu4 = reinterpret_cast<const f32x4*>(wu + tid * D_);
        float acc = 0.f;
#pragma unroll
        for (int c = 0; c < D_ / 4; ++c) {
            f32x4 a = uv4[c];
            f32x4 w = wu4[c];
            acc = __builtin_fmaf(a[0], w[0], acc);
            acc = __builtin_fmaf(a[1], w[1], acc);
            acc = __builtin_fmaf(a[2], w[2], acc);
            acc = __builtin_fmaf(a[3], w[3], acc);
        }
        wup_s[tid] = acc + bw[tid];
    }

    // ---- per-lane vw for units u = 16n + 4g + r; Mb bound ----
    f32x4 vwl2[4];
#pragma unroll
    for (int n = 0; n < 4; ++n) {
#pragma unroll
        for (int r = 0; r < 4; ++r) {
            const int uu = 16 * n + 4 * g + r;
            const bool uv = (uu < U_);
            vwl2[n][r] = uv ? vw[uu] : 0.f;
        }
    }
    float Mb = 0.f;
#pragma unroll
    for (int n = 0; n < 4; ++n)
#pragma unroll
        for (int r = 0; r < 4; ++r) Mb += fabsf(vwl2[n][r]);
    Mb += __shfl_xor(Mb, 16);
    Mb += __shfl_xor(Mb, 32);

    short8 a2ones;
#pragma unroll
    for (int i = 0; i < 8; ++i) a2ones[i] = (short)0x3F80;

    __syncthreads();

    // gl2 from LDS (broadcast reads)
    f32x4 gl2[4];
#pragma unroll
    for (int n = 0; n < 4; ++n) {
#pragma unroll
        for (int r = 0; r < 4; ++r) {
            const int uu = 16 * n + 4 * g + r;
            gl2[n][r] = (uu < U_) ? wup_s[uu] : 0.f;
        }
    }

    // ---- main: 4 m-tiles, linear-load -> LDS bounce -> fragments ----
    f32x4 pool[7];
#pragma unroll
    for (int j = 0; j < 7; ++j) pool[j] = zero4;
    float tsum = 0.f;

    f32x4 X[7];
    STAGE_READ(yA, y6A, X);
    LOADY(yA, y6A, 2);
    COMPUTE_M(X);

    STAGE_READ(yB, y6B, X);
    LOADY(yB, y6B, 3);
    COMPUTE_M(X);

    STAGE_READ(yA, y6A, X);
    COMPUTE_M(X);

    STAGE_READ(yB, y6B, X);
    COMPUTE_M(X);

    // ---- epilogue: li-direction reductions via DPP (VALU only) ----
    const float inv = 1.0f / fold16(tsum);
#pragma unroll
    for (int j = 0; j < 7; ++j) {
#pragma unroll
        for (int c = 0; c < 4; ++c) pool[j][c] = fold16(pool[j][c]);
    }

    // ---- store via per-wave LDS bounce (coalesced) ----
    if (li == 0) {
#pragma unroll
        for (int j = 0; j < 6; ++j) {
#pragma unroll
            for (int c = 0; c < 4; ++c) {
                const int k = 32 * (j >> 1) + 16 * (j & 1) + 4 * g + c;
                poolbuf[wid][k] = pool[j][c];
            }
        }
        if (g == 0) {
#pragma unroll
            for (int c = 0; c < 4; ++c) poolbuf[wid][96 + c] = pool[6][c];
        }
    }
    asm volatile("s_waitcnt lgkmcnt(0)" ::: "memory");

    float* po = out + ((size_t)b * S_ + s) * D_;
    po[l] = poolbuf[wid][l] * inv;
    if (l < D_ - SEC_) po[SEC_ + l] = poolbuf[wid][SEC_ + l] * inv;
}

extern "C" void kernel_launch(void* const* d_in, const int* in_sizes, int n_in,
                              void* d_out, int out_size, void* d_ws, size_t ws_size,
                              hipStream_t stream) {
    const float* sent = (const float*)d_in[0];
    const float* uvec = (const float*)d_in[1];
    const float* vw   = (const float*)d_in[2];
    const float* wh   = (const float*)d_in[3];
    const float* wu   = (const float*)d_in[4];
    const float* bw   = (const float*)d_in[5];
    float* out = (float*)d_out;

    attn_pool_v10<<<dim3(B_ * S_ / 4), dim3(256), 0, stream>>>(
        sent, uvec, vw, wh, wu, bw, out);
}

// Round 11
// 41.971 us; speedup vs baseline: 1.2849x; 1.0173x over previous
//
#include <hip/hip_runtime.h>
#include <hip/hip_bf16.h>

#define B_   256
#define T_   2048
#define D_   100
#define U_   50
#define S_   32
#define SEC_ 64

typedef __attribute__((ext_vector_type(8))) short short8;
typedef __attribute__((ext_vector_type(4))) float f32x4;

__device__ __forceinline__ float fast_tanh(float x) {
    // tanh(x) = 1 - 2/(1 + e^{2x}); safe at +-inf
    float e = __expf(2.0f * x);
    return 1.0f - 2.0f * __builtin_amdgcn_rcpf(1.0f + e);
}

__device__ __forceinline__ short f2bf(float f) {
    union { __hip_bfloat16 h; unsigned short u; } cv;
    cv.h = __float2bfloat16(f);  // RNE
    return (short)cv.u;
}

__device__ __forceinline__ short8 pack8(f32x4 a, f32x4 b) {
    short8 r;
    r[0] = f2bf(a[0]); r[1] = f2bf(a[1]); r[2] = f2bf(a[2]); r[3] = f2bf(a[3]);
    r[4] = f2bf(b[0]); r[5] = f2bf(b[1]); r[6] = f2bf(b[2]); r[7] = f2bf(b[3]);
    return r;
}

// VALU lane-reduction over the 16 lanes of a DPP row (li direction).
template<int CTRL>
__device__ __forceinline__ float ror_add(float v) {
    union { float f; int i; } in, out;
    in.f = v;
    out.i = __builtin_amdgcn_update_dpp(0, in.i, CTRL, 0xF, 0xF, true);
    return v + out.f;
}
__device__ __forceinline__ float fold16(float v) {
    v = ror_add<0x128>(v);  // row_ror:8
    v = ror_add<0x124>(v);  // row_ror:4
    v = ror_add<0x122>(v);  // row_ror:2
    v = ror_add<0x121>(v);  // row_ror:1
    return v;
}

// Wave-LINEAR global load of one 16x100 m-tile (1600 floats):
// 6 x f32x4 (1024 B contiguous each) + 1 x f32 (256 B contiguous).
// m-tiles are contiguous across the wave's 2-section slab (q = 0..7).
#define LOADY(Y, Y6, qq) do {                                            \
    const float* p_ = secm + 1600 * (qq);                                \
    Y[0] = *reinterpret_cast<const f32x4*>(p_ + 4 * l);                  \
    Y[1] = *reinterpret_cast<const f32x4*>(p_ + 256 + 4 * l);            \
    Y[2] = *reinterpret_cast<const f32x4*>(p_ + 512 + 4 * l);            \
    Y[3] = *reinterpret_cast<const f32x4*>(p_ + 768 + 4 * l);            \
    Y[4] = *reinterpret_cast<const f32x4*>(p_ + 1024 + 4 * l);           \
    Y[5] = *reinterpret_cast<const f32x4*>(p_ + 1280 + 4 * l);           \
    Y6   = p_[1536 + l];                                                 \
} while (0)

// Bounce linear regs through wave-private LDS; read back fragment layout
// X[j] = row li, cols 4g+16j. DS ops in a wave are in-order -> the reads
// of tile q complete before tile q+1's writes land; no extra sync needed.
#define STAGE_READ(Y, Y6, X) do {                                        \
    _Pragma("unroll")                                                    \
    for (int j = 0; j < 6; ++j)                                          \
        *reinterpret_cast<f32x4*>(sb + 256 * j + 4 * l) = Y[j];          \
    sb[1536 + l] = Y6;                                                   \
    asm volatile("s_waitcnt lgkmcnt(0)" ::: "memory");                   \
    _Pragma("unroll")                                                    \
    for (int j = 0; j < 6; ++j)                                          \
        X[j] = *reinterpret_cast<const f32x4*>(sb + li * 100 + 4 * g + 16 * j); \
    X[6] = *reinterpret_cast<const f32x4*>(sb + li * 100 + 96) * mg;     \
} while (0)

// Per-m-tile compute, shfl-free: swapped MFMA puts units on rows,
// word=li on cols; ones-MFMA reduces units; p lands in the pooling lane.
#define COMPUTE_M(X) do {                                                \
    short8 af[4];                                                        \
    af[0] = pack8(X[0], X[1]);                                           \
    af[1] = pack8(X[2], X[3]);                                           \
    af[2] = pack8(X[4], X[5]);                                           \
    af[3] = pack8(X[6], zero4);                                          \
    f32x4 acc[4];                                                        \
    _Pragma("unroll")                                                    \
    for (int n = 0; n < 4; ++n) acc[n] = (f32x4){0.f, 0.f, 0.f, 0.f};    \
    _Pragma("unroll")                                                    \
    for (int ks = 0; ks < 4; ++ks) {                                     \
        _Pragma("unroll")                                                \
        for (int n = 0; n < 4; ++n) {                                    \
            acc[n] = __builtin_amdgcn_mfma_f32_16x16x32_bf16(            \
                whb[n * 4 + ks][l], af[ks], acc[n], 0, 0, 0);            \
        }                                                                \
    }                                                                    \
    f32x4 t[4];                                                          \
    _Pragma("unroll")                                                    \
    for (int n = 0; n < 4; ++n) {                                        \
        _Pragma("unroll")                                                \
        for (int r = 0; r < 4; ++r)                                      \
            t[n][r] = vwl2[n][r] * fast_tanh(acc[n][r] + gl2[n][r]);     \
    }                                                                    \
    f32x4 e4 = (f32x4){0.f, 0.f, 0.f, 0.f};                              \
    e4 = __builtin_amdgcn_mfma_f32_16x16x32_bf16(                        \
        a2ones, pack8(t[0], t[1]), e4, 0, 0, 0);                         \
    e4 = __builtin_amdgcn_mfma_f32_16x16x32_bf16(                        \
        a2ones, pack8(t[2], t[3]), e4, 0, 0, 0);                         \
    const float p = __expf(e4[0] - Mb);                                  \
    tsum += p;                                                           \
    _Pragma("unroll")                                                    \
    for (int j = 0; j < 7; ++j)                                          \
        pool[j] = pool[j] + X[j] * p;                                    \
} while (0)

// Per-section epilogue: DPP folds (VALU), LDS bounce, coalesced store,
// reset accumulators. Wave-private; no block barrier.
#define EPILOG(PO) do {                                                  \
    const float inv_ = 1.0f / fold16(tsum);                              \
    _Pragma("unroll")                                                    \
    for (int j = 0; j < 7; ++j) {                                        \
        _Pragma("unroll")                                                \
        for (int c = 0; c < 4; ++c) pool[j][c] = fold16(pool[j][c]);     \
    }                                                                    \
    if (li == 0) {                                                       \
        _Pragma("unroll")                                                \
        for (int j = 0; j < 6; ++j) {                                    \
            _Pragma("unroll")                                            \
            for (int c = 0; c < 4; ++c) {                                \
                const int k = 32 * (j >> 1) + 16 * (j & 1) + 4 * g + c;  \
                poolbuf[wid][k] = pool[j][c];                            \
            }                                                            \
        }                                                                \
        if (g == 0) {                                                    \
            _Pragma("unroll")                                            \
            for (int c = 0; c < 4; ++c) poolbuf[wid][96 + c] = pool[6][c]; \
        }                                                                \
    }                                                                    \
    asm volatile("s_waitcnt lgkmcnt(0)" ::: "memory");                   \
    {                                                                    \
        float* po_ = (PO);                                               \
        po_[l] = poolbuf[wid][l] * inv_;                                 \
        if (l < D_ - SEC_) po_[SEC_ + l] = poolbuf[wid][SEC_ + l] * inv_; \
    }                                                                    \
    _Pragma("unroll")                                                    \
    for (int j = 0; j < 7; ++j) pool[j] = zero4;                         \
    tsum = 0.f;                                                          \
} while (0)

// Fused streaming kernel. Block = 4 waves; each wave owns 2 consecutive
// sections (8 contiguous m-tiles) -> prologue amortized 2x, generation
// count per CU halved, ping-pong prefetch runs across the section boundary.
__global__ __launch_bounds__(256, 2) void attn_pool_v11(
    const float* __restrict__ sent,     // [B, T, D]
    const float* __restrict__ user_vec, // [B, USER_DIM]
    const float* __restrict__ vw,       // [U]
    const float* __restrict__ wh,       // [U, D]
    const float* __restrict__ wu,       // [U, USER_DIM]
    const float* __restrict__ bw,       // [U]
    float* __restrict__ out) {          // [B, S, D]
    __shared__ short8 whb[16][64];                    // 16 KB
    __shared__ __align__(16) float xstage[4][1600];   // 25.6 KB (wave-private)
    __shared__ float wup_s[64];
    __shared__ float poolbuf[4][128];                 // 2 KB

    const int tid = threadIdx.x;
    const int wid = tid >> 6;
    const int l   = tid & 63;
    const int g   = l >> 4;
    const int li  = l & 15;

    const int W  = blockIdx.x * 4 + wid;  // 0..4095
    const int b  = W >> 4;                // 16 waves per batch row
    const int sp = W & 15;                // section pair
    const float* secm = sent + ((size_t)b * T_ + (size_t)(2 * sp) * SEC_) * D_;
    float* sb = &xstage[wid][0];

    const float mg = (g == 0) ? 1.f : 0.f;
    const f32x4 zero4 = (f32x4){0.f, 0.f, 0.f, 0.f};

    // ---- issue first two m-tile loads (wave-linear) ----
    f32x4 yA[6], yB[6];
    float y6A, y6B;
    LOADY(yA, y6A, 0);
    LOADY(yB, y6B, 1);

    // ---- prologue A: wh(f32) -> bf16 fragments in LDS ----
#pragma unroll
    for (int j = 0; j < 4; ++j) {
        const int idx = tid + 256 * j;
        const int pli = idx & 15;
        const int pg  = (idx >> 4) & 3;
        const int pks = (idx >> 6) & 3;
        const int pn  = idx >> 8;
        const int u   = 16 * pn + pli;
        const bool uv = (u < U_);
        const int k0  = 32 * pks + 4 * pg;
        const bool v1 = uv && (k0 <= D_ - 4);
        const bool v2 = uv && (k0 + 16 <= D_ - 4);
        const float* rowp = wh + (uv ? u : 0) * D_;
        f32x4 a  = *reinterpret_cast<const f32x4*>(rowp + (v1 ? k0 : 0));
        f32x4 bb = *reinterpret_cast<const f32x4*>(rowp + (v2 ? k0 + 16 : 0));
        a  *= (v1 ? 1.f : 0.f);
        bb *= (v2 ? 1.f : 0.f);
        whb[idx >> 6][idx & 63] = pack8(a, bb);
    }

    // ---- prologue B: fused wu_proj (one unit per lane, tid<50) ----
    if (tid < U_) {
        const f32x4* uv4 = reinterpret_cast<const f32x4*>(user_vec + b * D_);
        const f32x4* wu4 = reinterpret_cast<const f32x4*>(wu + tid * D_);
        float acc = 0.f;
#pragma unroll
        for (int c = 0; c < D_ / 4; ++c) {
            f32x4 a = uv4[c];
            f32x4 w = wu4[c];
            acc = __builtin_fmaf(a[0], w[0], acc);
            acc = __builtin_fmaf(a[1], w[1], acc);
            acc = __builtin_fmaf(a[2], w[2], acc);
            acc = __builtin_fmaf(a[3], w[3], acc);
        }
        wup_s[tid] = acc + bw[tid];
    }

    // ---- per-lane vw for units u = 16n + 4g + r; Mb bound ----
    f32x4 vwl2[4];
#pragma unroll
    for (int n = 0; n < 4; ++n) {
#pragma unroll
        for (int r = 0; r < 4; ++r) {
            const int uu = 16 * n + 4 * g + r;
            vwl2[n][r] = (uu < U_) ? vw[uu] : 0.f;
        }
    }
    float Mb = 0.f;
#pragma unroll
    for (int n = 0; n < 4; ++n)
#pragma unroll
        for (int r = 0; r < 4; ++r) Mb += fabsf(vwl2[n][r]);
    Mb += __shfl_xor(Mb, 16);
    Mb += __shfl_xor(Mb, 32);

    short8 a2ones;
#pragma unroll
    for (int i = 0; i < 8; ++i) a2ones[i] = (short)0x3F80;

    __syncthreads();

    // gl2 from LDS (broadcast reads)
    f32x4 gl2[4];
#pragma unroll
    for (int n = 0; n < 4; ++n) {
#pragma unroll
        for (int r = 0; r < 4; ++r) {
            const int uu = 16 * n + 4 * g + r;
            gl2[n][r] = (uu < U_) ? wup_s[uu] : 0.f;
        }
    }

    // ---- main: 8 m-tiles (2 sections) straight-line ping-pong ----
    f32x4 pool[7];
#pragma unroll
    for (int j = 0; j < 7; ++j) pool[j] = zero4;
    float tsum = 0.f;

    float* po = out + ((size_t)b * S_ + 2 * sp) * D_;
    f32x4 X[7];

#pragma unroll
    for (int q = 0; q < 8; q += 2) {
        STAGE_READ(yA, y6A, X);
        if (q + 2 < 8) LOADY(yA, y6A, q + 2);
        COMPUTE_M(X);

        STAGE_READ(yB, y6B, X);
        if (q + 3 < 8) LOADY(yB, y6B, q + 3);
        COMPUTE_M(X);

        if ((q & 3) == 2) {  // tiles 0-3 / 4-7 complete -> section epilogue
            EPILOG(po);
            po += D_;
        }
    }
}

extern "C" void kernel_launch(void* const* d_in, const int* in_sizes, int n_in,
                              void* d_out, int out_size, void* d_ws, size_t ws_size,
                              hipStream_t stream) {
    const float* sent = (const float*)d_in[0];
    const float* uvec = (const float*)d_in[1];
    const float* vw   = (const float*)d_in[2];
    const float* wh   = (const float*)d_in[3];
    const float* wu   = (const float*)d_in[4];
    const float* bw   = (const float*)d_in[5];
    float* out = (float*)d_out;

    attn_pool_v11<<<dim3(B_ * S_ / 8), dim3(256), 0, stream>>>(
        sent, uvec, vw, wh, wu, bw, out);
}